// Round 15
// baseline (139.441 us; speedup 1.0000x reference)
//
#include <hip/hip_runtime.h>
#include <stdint.h>

typedef unsigned short u16;
typedef float  f32x4  __attribute__((ext_vector_type(4)));
typedef float  f32x16 __attribute__((ext_vector_type(16)));
typedef __bf16 bf16x8 __attribute__((ext_vector_type(8)));
typedef __bf16 bf16x4 __attribute__((ext_vector_type(4)));
typedef unsigned short u16x8 __attribute__((ext_vector_type(8)));
typedef unsigned short u16x4v __attribute__((ext_vector_type(4)));
typedef unsigned int u32x2 __attribute__((ext_vector_type(2)));
typedef unsigned int u32x4 __attribute__((ext_vector_type(4)));

#define S_LEN 2048
#define E_DIM 2048
#define HD    128
#define QH    16
#define KVH   4
#define KVD   512
#define NQKV  3072
#define QK_SCALE 0.08838834764831845f  // 1/sqrt(128)

#define AS1 __attribute__((address_space(1)))
#define AS3 __attribute__((address_space(3)))

__device__ __forceinline__ u16 f2bf(float f) {
  union { float f; uint32_t u; } v; v.f = f;
  return (u16)((v.u + 0x7FFFu + ((v.u >> 16) & 1u)) >> 16);
}

// ---------------- fused cast fp32->bf16 (5 tensors) + RoPE trig table ----------
__global__ void cast_all_kernel(const float* __restrict__ x, const float* __restrict__ Wq,
                                const float* __restrict__ Wk, const float* __restrict__ Wv,
                                const float* __restrict__ Wo,
                                u16* __restrict__ xb, u16* __restrict__ Wcat,
                                u16* __restrict__ Wob, float2* __restrict__ tab) {
  int i = blockIdx.x * blockDim.x + threadIdx.x;
  if (i >= 3670016) {           // rope table
    int j = i - 3670016;        // 0 .. 131071
    int s = j >> 6, pidx = j & 63;
    float inv = exp2f((float)pidx * (-13.287712379549449f / 64.0f));  // 10000^(-p/64)
    float sn, cs;
    sincosf((float)s * inv, &sn, &cs);
    tab[j] = make_float2(cs, sn);
    return;
  }
  const float* src; u16* dst;
  if (i < (1 << 20))                       { src = x  + (size_t)i * 4;  dst = xb + (size_t)i * 4; }
  else if (i < (2 << 20))                  { size_t j = i - (1 << 20);  src = Wq + j * 4; dst = Wcat + j * 4; }
  else if (i < (2 << 20) + (1 << 18))      { size_t j = i - (2 << 20);  src = Wk + j * 4; dst = Wcat + (size_t)E_DIM * E_DIM + j * 4; }
  else if (i < (2 << 20) + (2 << 18))      { size_t j = i - (2 << 20) - (1 << 18); src = Wv + j * 4; dst = Wcat + (size_t)(E_DIM + KVD) * E_DIM + j * 4; }
  else                                     { size_t j = i - (2 << 20) - (2 << 18); src = Wo + j * 4; dst = Wob + j * 4; }
  float4 f = *reinterpret_cast<const float4*>(src);
  u16x4v o;
  o[0] = f2bf(f.x); o[1] = f2bf(f.y); o[2] = f2bf(f.z); o[3] = f2bf(f.w);
  *reinterpret_cast<u16x4v*>(dst) = o;
}

// ---------------- GEMM: C[M,N] = A[M,K] * B[N,K]^T, bf16 in -------------------
// 64x128 tile (M x N), BK=64, 256 threads = 4 waves (each owns 64x32).
// MODE 0: fp32 C + bias.  MODE 2: fused QKV epilogue (RoPE + V-transpose).
template<bool BIAS, int MODE>
__global__ __launch_bounds__(256) void gemm_bt_kernel(
    const u16* __restrict__ A, const u16* __restrict__ B,
    float* __restrict__ C, const float* __restrict__ bias,
    const float2* __restrict__ tab, u16* __restrict__ qb,
    u16* __restrict__ kb, u16* __restrict__ vTp,
    int M, int N, int K)
{
  __shared__ u16 As[2][64 * 64];    // 8 KB x2
  __shared__ u16 Bs[2][128 * 64];   // 16 KB x2

  const int tid  = threadIdx.x;
  const int lane = tid & 63;
  const int wid  = tid >> 6;        // 0..3
  const int wc   = wid * 32;
  const int lr   = lane & 15;
  const int kg   = lane >> 4;
  const int sw   = lr & 7;

  const int bm = blockIdx.y * 64;
  const int bn = blockIdx.x * 128;

  f32x4 acc[4][2];
  #pragma unroll
  for (int r = 0; r < 4; ++r)
    #pragma unroll
    for (int c = 0; c < 2; ++c) acc[r][c] = (f32x4){0.f, 0.f, 0.f, 0.f};

  const int srow   = wid * 8 + (lane >> 3);
  const int schunk = (lane & 7) ^ (lane >> 3);

  const u16* gA = A + (size_t)(bm + srow) * K + schunk * 8;
  const u16* gB = B + (size_t)(bn + srow) * K + schunk * 8;

  auto stage = [&](int buf, int kt) {
    #pragma unroll
    for (int i = 0; i < 2; ++i)
      __builtin_amdgcn_global_load_lds(
          (const AS1 void*)(gA + (size_t)i * 32 * K + kt),
          (AS3 void*)(&As[buf][(wid*8 + i*32) * 64]), 16, 0, 0);
    #pragma unroll
    for (int i = 0; i < 4; ++i)
      __builtin_amdgcn_global_load_lds(
          (const AS1 void*)(gB + (size_t)i * 32 * K + kt),
          (AS3 void*)(&Bs[buf][(wid*8 + i*32) * 64]), 16, 0, 0);
  };

  stage(0, 0);
  __syncthreads();

  int cur = 0;
  for (int kt = 0; kt < K; kt += 64) {
    if (kt + 64 < K) stage(cur ^ 1, kt + 64);
    #pragma unroll
    for (int kk = 0; kk < 2; ++kk) {
      bf16x8 af[4], bfr[2];
      #pragma unroll
      for (int r = 0; r < 4; ++r)
        af[r] = *reinterpret_cast<const bf16x8*>(
            &As[cur][(r*16 + lr)*64 + ((kk*4 + kg) ^ sw)*8]);
      #pragma unroll
      for (int c = 0; c < 2; ++c)
        bfr[c] = *reinterpret_cast<const bf16x8*>(
            &Bs[cur][(wc + c*16 + lr)*64 + ((kk*4 + kg) ^ sw)*8]);
      #pragma unroll
      for (int r = 0; r < 4; ++r)
        #pragma unroll
        for (int c = 0; c < 2; ++c)
          acc[r][c] = __builtin_amdgcn_mfma_f32_16x16x32_bf16(af[r], bfr[c], acc[r][c], 0, 0, 0);
    }
    __syncthreads();
    cur ^= 1;
  }

  const int crow = kg * 4;
  #pragma unroll
  for (int r = 0; r < 4; ++r) {
    #pragma unroll
    for (int c = 0; c < 2; ++c) {
      int gr = bm + r*16 + crow;
      int gc = bn + wc + c*16 + lr;
      if constexpr (MODE == 0) {
        float badd = BIAS ? bias[gc] : 0.0f;
        #pragma unroll
        for (int reg = 0; reg < 4; ++reg)
          C[(size_t)(gr + reg)*N + gc] = acc[r][c][reg] + badd;
      } else {  // MODE 2: fused QKV epilogue
        if (gc < E_DIM + KVD) {
          int pidx = (gc & 127) >> 1;
          bool odd = lr & 1;
          #pragma unroll
          for (int reg = 0; reg < 4; ++reg) {
            float val = acc[r][c][reg];
            float oth = __shfl_xor(val, 1);
            float2 cs = tab[(gr + reg) * 64 + pidx];
            float o = odd ? (oth * cs.y + val * cs.x)
                          : (val * cs.x - oth * cs.y);
            if (gc < E_DIM)
              qb[(size_t)(gr + reg) * E_DIM + gc] = f2bf(o * QK_SCALE);
            else
              kb[(size_t)(gr + reg) * KVD + (gc - E_DIM)] = f2bf(o);
          }
        } else {
          bf16x4 pk;
          #pragma unroll
          for (int reg = 0; reg < 4; ++reg) pk[reg] = (__bf16)acc[r][c][reg];
          *reinterpret_cast<bf16x4*>(
              &vTp[(size_t)(gc - E_DIM - KVD) * S_LEN + gr]) = pk;
        }
      }
    }
  }
}

// ---------------- Flash attention (causal, GQA 4:1) -- 32x32 core, 48 KB LDS ---
// 512 blocks (flip-paired qt), 256 thr = 4 waves (q-rowgroup x kv-half, r14
// core). LDS cut to 48 KB -> 2 blocks/CU co-resident; CU c hosts blocks
// {c, c+256} = complementary {qt, 31-qt} running CONCURRENTLY (8 waves/CU).
// K dbuf via global_load_lds w16 (src XOR swizzle, linear dest -- r7-proven);
// V single-buffered reg-staged (barrier, v_write, barrier -- r7 ordering).
// In-register P-exchange (no Ps), defer-max, end-merge aliasing Ks/VTs.
__global__ __launch_bounds__(256, 2) void attn_kernel(
    const u16* __restrict__ Q, const u16* __restrict__ Kc,
    const u16* __restrict__ VT, u16* __restrict__ Out)
{
  __shared__ u16 Ks[2][64 * 128];   // 16KB x2; merge: f32 Obuf 64x128 (32KB)
  __shared__ u16 VTs[128 * 64];     // 16KB single; merge: Lm/Ll

  const int x = blockIdx.x;
  int qt, h;
  if (x < 256) { qt = x & 31; h = x >> 5; }
  else         { int xp = x - 256; qt = 31 - (xp & 31); h = 8 + (xp >> 5); }
  const int kvh = h >> 2;
  const int tid  = threadIdx.x;
  const int lane = tid & 63;
  const int wid  = tid >> 6;
  const int kvg  = wid & 1;      // kv-half of each tile
  const int rowg = wid >> 1;     // q-row group (32 rows)
  const int ln   = lane & 31;
  const int hi   = lane >> 5;

  const int NT = qt + 1;

  // Q B-frags: col=q=ln, k = ks*16 + hi*8 + j
  bf16x8 qf[8];
  {
    const u16* qa = Q + (size_t)(qt*64 + rowg*32 + ln) * E_DIM + h * HD + hi * 8;
    #pragma unroll
    for (int ks = 0; ks < 8; ++ks)
      qf[ks] = *reinterpret_cast<const bf16x8*>(qa + ks * 16);
  }

  f32x16 o4[4];
  #pragma unroll
  for (int d = 0; d < 4; ++d)
    #pragma unroll
    for (int r = 0; r < 16; ++r) o4[d][r] = 0.f;
  float mr = -1e30f, ls = 0.f;

  const u16* kbase = Kc + kvh * HD;
  const u16* vbase = VT + (size_t)(kvh * HD) * S_LEN;

  // K tile DMA (16KB): wave w issue j covers rows j*16+w*4..+4 (1KB each).
  // lane l -> row +(l>>4), LDS chunk l&15; src chunk = (l&15)^(row&7).
  const int kr_off = lane >> 4;
  const int kchunk = lane & 15;
  auto k_dma = [&](int buf, int t) {
    #pragma unroll
    for (int j = 0; j < 4; ++j) {
      int r0 = j*16 + wid*4;
      int r  = r0 + kr_off;
      const u16* src = kbase + (size_t)(t*64 + r) * KVD + ((kchunk ^ (r & 7)) * 8);
      __builtin_amdgcn_global_load_lds((const AS1 void*)src,
          (AS3 void*)(&Ks[buf][r0 * 128]), 16, 0, 0);
    }
  };

  // V global->reg (coalesced along kv); reg->VTs with chunk^(d&7).
  u16x8 vreg[4];
  auto v_load = [&](int t) {
    #pragma unroll
    for (int i = 0; i < 4; ++i) {
      int c = i * 256 + tid;
      vreg[i] = *reinterpret_cast<const u16x8*>(
          vbase + (size_t)(c >> 3) * S_LEN + t*64 + (c & 7) * 8);
    }
  };
  auto v_write = [&]() {
    #pragma unroll
    for (int i = 0; i < 4; ++i) {
      int c = i * 256 + tid;
      int d = c >> 3;
      *reinterpret_cast<u16x8*>(&VTs[d*64 + ((c & 7) ^ (d & 7)) * 8]) = vreg[i];
    }
  };

  k_dma(0, 0);
  v_load(0);
  v_write();
  __syncthreads();   // K(0) DMA drained, VTs(0) visible

  const int krow = kvg*32 + ln;   // K A-frag row (kv within tile)

  int p = 0;
  for (int t = 0; t < NT; ++t) {
    const bool lastt = (t + 1 == NT);
    if (!lastt) { k_dma(p ^ 1, t + 1); v_load(t + 1); }  // in flight over compute

    // S^T = mfma(K, Q): lane (ln,hi) -> S[kv = kvg*32+4hi+(reg&3)+8(reg>>2)][q=ln]
    f32x16 st;
    #pragma unroll
    for (int r = 0; r < 16; ++r) st[r] = 0.f;
    __builtin_amdgcn_s_setprio(1);
    #pragma unroll
    for (int ks = 0; ks < 8; ++ks) {
      bf16x8 kfr = *reinterpret_cast<const bf16x8*>(
          &Ks[p][krow*128 + ((ks*2 + hi) ^ (ln & 7))*8]);
      st = __builtin_amdgcn_mfma_f32_32x32x16_bf16(kfr, qf[ks], st, 0, 0, 0);
    }
    __builtin_amdgcn_s_setprio(0);

    if (t == qt) {  // causal mask on diagonal tile
      #pragma unroll
      for (int reg = 0; reg < 16; ++reg) {
        int kvl = kvg*32 + 4*hi + (reg & 3) + 8*(reg >> 2);
        if (kvl > rowg*32 + ln) st[reg] = -1e30f;
      }
    }

    // row max for q=ln over this wave's 32 kv: in-reg tree + 1 cross-hi shfl
    float pm = -1e30f;
    #pragma unroll
    for (int reg = 0; reg < 16; ++reg) pm = fmaxf(pm, st[reg]);
    pm = fmaxf(pm, __shfl_xor(pm, 32));

    if (!__all(pm - mr <= 8.0f)) {  // defer-max rescale (rare)
      float nm = fmaxf(mr, pm);
      float alpha = __expf(mr - nm);
      ls *= alpha;
      mr = nm;
      #pragma unroll
      for (int reg = 0; reg < 16; ++reg) {
        int crow = (reg & 3) + 8*(reg >> 2) + 4*hi;
        float ar = __shfl(alpha, crow);
        #pragma unroll
        for (int d = 0; d < 4; ++d) o4[d][reg] *= ar;
      }
    }

    float pv[16];
    float sum = 0.f;
    #pragma unroll
    for (int reg = 0; reg < 16; ++reg) {
      pv[reg] = __expf(st[reg] - mr);
      sum += pv[reg];
    }
    sum += __shfl_xor(sum, 32);
    ls += sum;

    // P -> A-frags in-register: pa[ks] = P[q=ln][kv = ks*16 + hi*8 + 0..7].
    // own groupA (regs 8ks..+3) = kv ks*16+4hi+0..3; groupB (regs 8ks+4..+7)
    // = kv ks*16+8+4hi+0..3. hi=0 sends B / keeps A; hi=1 sends A / keeps B.
    bf16x8 pa[2];
    #pragma unroll
    for (int ks = 0; ks < 2; ++ks) {
      bf16x4 A4, B4;
      #pragma unroll
      for (int j = 0; j < 4; ++j) {
        A4[j] = (__bf16)pv[ks*8 + j];
        B4[j] = (__bf16)pv[ks*8 + 4 + j];
      }
      u32x2 uA = __builtin_bit_cast(u32x2, A4);
      u32x2 uB = __builtin_bit_cast(u32x2, B4);
      unsigned sx = hi ? uA[0] : uB[0];
      unsigned sy = hi ? uA[1] : uB[1];
      unsigned rx = __shfl_xor(sx, 32);
      unsigned ry = __shfl_xor(sy, 32);
      u32x4 w;
      w[0] = hi ? rx : uA[0];
      w[1] = hi ? ry : uA[1];
      w[2] = hi ? uB[0] : rx;
      w[3] = hi ? uB[1] : ry;
      pa[ks] = __builtin_bit_cast(bf16x8, w);
    }

    // O += P * V over this wave's kv-half
    __builtin_amdgcn_s_setprio(1);
    #pragma unroll
    for (int d = 0; d < 4; ++d) {
      int vrow = d*32 + ln;
      #pragma unroll
      for (int ks = 0; ks < 2; ++ks) {
        bf16x8 vb = *reinterpret_cast<const bf16x8*>(
            &VTs[vrow*64 + ((kvg*4 + ks*2 + hi) ^ (ln & 7))*8]);
        o4[d] = __builtin_amdgcn_mfma_f32_32x32x16_bf16(pa[ks], vb, o4[d], 0, 0, 0);
      }
    }
    __builtin_amdgcn_s_setprio(0);

    if (!lastt) {
      __syncthreads();   // PV(t) done everywhere; K(t+1) DMA drained
      v_write();         // VTs <- V(t+1)
      __syncthreads();   // VTs visible
      p ^= 1;
    }
  }

  // -------- merge kv-halves: kvg=1 publishes, kvg=0 combines + writes --------
  __syncthreads();                         // all reads of Ks/VTs done
  float* Obuf = (float*)&Ks[0][0];         // 64 x 128 f32 = 32 KB exact
  float* Lbuf = (float*)&VTs[0];           // Lm[64] | Ll[64]
  if (kvg == 1) {
    if (hi == 0) { Lbuf[rowg*32 + ln] = mr; Lbuf[64 + rowg*32 + ln] = ls; }
    #pragma unroll
    for (int reg = 0; reg < 16; ++reg) {
      int crow = (reg & 3) + 8*(reg >> 2) + 4*hi;
      #pragma unroll
      for (int d = 0; d < 4; ++d)
        Obuf[(rowg*32 + crow)*128 + d*32 + ln] = o4[d][reg];
    }
  }
  __syncthreads();
  if (kvg == 0) {
    float mB = Lbuf[rowg*32 + ln];        // partner stats for q = ln
    float lB = Lbuf[64 + rowg*32 + ln];
    float m  = fmaxf(mr, mB);
    float a0 = __expf(mr - m);
    float a1 = __expf(mB - m);
    float inv = 1.0f / (ls*a0 + lB*a1);
    #pragma unroll
    for (int reg = 0; reg < 16; ++reg) {
      int crow = (reg & 3) + 8*(reg >> 2) + 4*hi;
      float a0r = __shfl(a0, crow);
      float a1r = __shfl(a1, crow);
      float ivr = __shfl(inv, crow);
      int grow = qt*64 + rowg*32 + crow;
      #pragma unroll
      for (int d = 0; d < 4; ++d) {
        float v = (o4[d][reg]*a0r +
                   Obuf[(rowg*32 + crow)*128 + d*32 + ln]*a1r) * ivr;
        Out[(size_t)grow * E_DIM + h * HD + d*32 + ln] =
            __builtin_bit_cast(u16, (__bf16)v);
      }
    }
  }
}

// ---------------- launch ----------------
extern "C" void kernel_launch(void* const* d_in, const int* in_sizes, int n_in,
                              void* d_out, int out_size, void* d_ws, size_t ws_size,
                              hipStream_t stream)
{
  const float* x  = (const float*)d_in[0];
  const float* Wq = (const float*)d_in[1];
  const float* Wk = (const float*)d_in[2];
  const float* Wv = (const float*)d_in[3];
  const float* Wo = (const float*)d_in[4];
  const float* bo = (const float*)d_in[5];
  float* out = (float*)d_out;

  char* w = (char*)d_ws;
  u16*    xb   = (u16*)(w);                   // 8 MB  x bf16 (2048x2048)
  u16*    Wcat = (u16*)(w + (8u  << 20));     // 12 MB [Wq;Wk;Wv] bf16 (3072x2048)
  u16*    Wob  = (u16*)(w + (20u << 20));     // 8 MB  Wo bf16
  float2* tab  = (float2*)(w + (28u << 20));  // 1 MB  rope table (2048x64)
  u16*    qb   = (u16*)(w + (30u << 20));     // 8 MB  q bf16 roped+scaled
  u16*    kb   = (u16*)(w + (38u << 20));     // 2 MB  k bf16 roped
  u16*    vT   = (u16*)(w + (40u << 20));     // 2 MB  v^T bf16 (512x2048)
  u16*    attn = (u16*)(w + (42u << 20));     // 8 MB  attention out bf16
  (void)ws_size; (void)in_sizes; (void)n_in; (void)out_size;

  cast_all_kernel<<<14848, 256, 0, stream>>>(x, Wq, Wk, Wv, Wo, xb, Wcat, Wob, tab);

  gemm_bt_kernel<false, 2><<<dim3(NQKV/128, S_LEN/64), 256, 0, stream>>>(
      xb, Wcat, nullptr, nullptr, tab, qb, kb, vT, S_LEN, NQKV, E_DIM);

  attn_kernel<<<512, 256, 0, stream>>>(qb, kb, vT, attn);

  gemm_bt_kernel<true, 0><<<dim3(E_DIM/128, S_LEN/64), 256, 0, stream>>>(
      attn, Wob, out, bo, nullptr, nullptr, nullptr, nullptr, S_LEN, E_DIM, E_DIM);
}

// Round 16
// 130.498 us; speedup vs baseline: 1.0685x; 1.0685x over previous
//
#include <hip/hip_runtime.h>
#include <stdint.h>

typedef unsigned short u16;
typedef float  f32x4  __attribute__((ext_vector_type(4)));
typedef float  f32x16 __attribute__((ext_vector_type(16)));
typedef __bf16 bf16x8 __attribute__((ext_vector_type(8)));
typedef __bf16 bf16x4 __attribute__((ext_vector_type(4)));
typedef unsigned short u16x8 __attribute__((ext_vector_type(8)));
typedef unsigned short u16x4v __attribute__((ext_vector_type(4)));
typedef unsigned int u32x2 __attribute__((ext_vector_type(2)));
typedef unsigned int u32x4 __attribute__((ext_vector_type(4)));

#define S_LEN 2048
#define E_DIM 2048
#define HD    128
#define QH    16
#define KVH   4
#define KVD   512
#define NQKV  3072
#define QK_SCALE 0.08838834764831845f  // 1/sqrt(128)

#define AS1 __attribute__((address_space(1)))
#define AS3 __attribute__((address_space(3)))

__device__ __forceinline__ u16 f2bf(float f) {
  union { float f; uint32_t u; } v; v.f = f;
  return (u16)((v.u + 0x7FFFu + ((v.u >> 16) & 1u)) >> 16);
}

// ---------------- fused cast fp32->bf16 (5 tensors) + RoPE trig table ----------
__global__ void cast_all_kernel(const float* __restrict__ x, const float* __restrict__ Wq,
                                const float* __restrict__ Wk, const float* __restrict__ Wv,
                                const float* __restrict__ Wo,
                                u16* __restrict__ xb, u16* __restrict__ Wcat,
                                u16* __restrict__ Wob, float2* __restrict__ tab) {
  int i = blockIdx.x * blockDim.x + threadIdx.x;
  if (i >= 3670016) {           // rope table
    int j = i - 3670016;        // 0 .. 131071
    int s = j >> 6, pidx = j & 63;
    float inv = exp2f((float)pidx * (-13.287712379549449f / 64.0f));  // 10000^(-p/64)
    float sn, cs;
    sincosf((float)s * inv, &sn, &cs);
    tab[j] = make_float2(cs, sn);
    return;
  }
  const float* src; u16* dst;
  if (i < (1 << 20))                       { src = x  + (size_t)i * 4;  dst = xb + (size_t)i * 4; }
  else if (i < (2 << 20))                  { size_t j = i - (1 << 20);  src = Wq + j * 4; dst = Wcat + j * 4; }
  else if (i < (2 << 20) + (1 << 18))      { size_t j = i - (2 << 20);  src = Wk + j * 4; dst = Wcat + (size_t)E_DIM * E_DIM + j * 4; }
  else if (i < (2 << 20) + (2 << 18))      { size_t j = i - (2 << 20) - (1 << 18); src = Wv + j * 4; dst = Wcat + (size_t)(E_DIM + KVD) * E_DIM + j * 4; }
  else                                     { size_t j = i - (2 << 20) - (2 << 18); src = Wo + j * 4; dst = Wob + j * 4; }
  float4 f = *reinterpret_cast<const float4*>(src);
  u16x4v o;
  o[0] = f2bf(f.x); o[1] = f2bf(f.y); o[2] = f2bf(f.z); o[3] = f2bf(f.w);
  *reinterpret_cast<u16x4v*>(dst) = o;
}

// ---------------- GEMM: C[M,N] = A[M,K] * B[N,K]^T, bf16 in -------------------
// 64x128 tile (M x N), BK=64, 256 threads = 4 waves (each owns 64x32).
// MODE 0: fp32 C + bias.  MODE 2: fused QKV epilogue (RoPE + V-transpose).
template<bool BIAS, int MODE>
__global__ __launch_bounds__(256) void gemm_bt_kernel(
    const u16* __restrict__ A, const u16* __restrict__ B,
    float* __restrict__ C, const float* __restrict__ bias,
    const float2* __restrict__ tab, u16* __restrict__ qb,
    u16* __restrict__ kb, u16* __restrict__ vTp,
    int M, int N, int K)
{
  __shared__ u16 As[2][64 * 64];    // 8 KB x2
  __shared__ u16 Bs[2][128 * 64];   // 16 KB x2

  const int tid  = threadIdx.x;
  const int lane = tid & 63;
  const int wid  = tid >> 6;        // 0..3
  const int wc   = wid * 32;
  const int lr   = lane & 15;
  const int kg   = lane >> 4;
  const int sw   = lr & 7;

  const int bm = blockIdx.y * 64;
  const int bn = blockIdx.x * 128;

  f32x4 acc[4][2];
  #pragma unroll
  for (int r = 0; r < 4; ++r)
    #pragma unroll
    for (int c = 0; c < 2; ++c) acc[r][c] = (f32x4){0.f, 0.f, 0.f, 0.f};

  const int srow   = wid * 8 + (lane >> 3);
  const int schunk = (lane & 7) ^ (lane >> 3);

  const u16* gA = A + (size_t)(bm + srow) * K + schunk * 8;
  const u16* gB = B + (size_t)(bn + srow) * K + schunk * 8;

  auto stage = [&](int buf, int kt) {
    #pragma unroll
    for (int i = 0; i < 2; ++i)
      __builtin_amdgcn_global_load_lds(
          (const AS1 void*)(gA + (size_t)i * 32 * K + kt),
          (AS3 void*)(&As[buf][(wid*8 + i*32) * 64]), 16, 0, 0);
    #pragma unroll
    for (int i = 0; i < 4; ++i)
      __builtin_amdgcn_global_load_lds(
          (const AS1 void*)(gB + (size_t)i * 32 * K + kt),
          (AS3 void*)(&Bs[buf][(wid*8 + i*32) * 64]), 16, 0, 0);
  };

  stage(0, 0);
  __syncthreads();

  int cur = 0;
  for (int kt = 0; kt < K; kt += 64) {
    if (kt + 64 < K) stage(cur ^ 1, kt + 64);
    #pragma unroll
    for (int kk = 0; kk < 2; ++kk) {
      bf16x8 af[4], bfr[2];
      #pragma unroll
      for (int r = 0; r < 4; ++r)
        af[r] = *reinterpret_cast<const bf16x8*>(
            &As[cur][(r*16 + lr)*64 + ((kk*4 + kg) ^ sw)*8]);
      #pragma unroll
      for (int c = 0; c < 2; ++c)
        bfr[c] = *reinterpret_cast<const bf16x8*>(
            &Bs[cur][(wc + c*16 + lr)*64 + ((kk*4 + kg) ^ sw)*8]);
      #pragma unroll
      for (int r = 0; r < 4; ++r)
        #pragma unroll
        for (int c = 0; c < 2; ++c)
          acc[r][c] = __builtin_amdgcn_mfma_f32_16x16x32_bf16(af[r], bfr[c], acc[r][c], 0, 0, 0);
    }
    __syncthreads();
    cur ^= 1;
  }

  const int crow = kg * 4;
  #pragma unroll
  for (int r = 0; r < 4; ++r) {
    #pragma unroll
    for (int c = 0; c < 2; ++c) {
      int gr = bm + r*16 + crow;
      int gc = bn + wc + c*16 + lr;
      if constexpr (MODE == 0) {
        float badd = BIAS ? bias[gc] : 0.0f;
        #pragma unroll
        for (int reg = 0; reg < 4; ++reg)
          C[(size_t)(gr + reg)*N + gc] = acc[r][c][reg] + badd;
      } else {  // MODE 2: fused QKV epilogue
        if (gc < E_DIM + KVD) {
          int pidx = (gc & 127) >> 1;
          bool odd = lr & 1;
          #pragma unroll
          for (int reg = 0; reg < 4; ++reg) {
            float val = acc[r][c][reg];
            float oth = __shfl_xor(val, 1);
            float2 cs = tab[(gr + reg) * 64 + pidx];
            float o = odd ? (oth * cs.y + val * cs.x)
                          : (val * cs.x - oth * cs.y);
            if (gc < E_DIM)
              qb[(size_t)(gr + reg) * E_DIM + gc] = f2bf(o * QK_SCALE);
            else
              kb[(size_t)(gr + reg) * KVD + (gc - E_DIM)] = f2bf(o);
          }
        } else {
          bf16x4 pk;
          #pragma unroll
          for (int reg = 0; reg < 4; ++reg) pk[reg] = (__bf16)acc[r][c][reg];
          *reinterpret_cast<bf16x4*>(
              &vTp[(size_t)(gc - E_DIM - KVD) * S_LEN + gr]) = pk;
        }
      }
    }
  }
}

// ---------------- Flash attention (causal, GQA 4:1) -- r14 core + QK ILP split -
// 512 blocks (flip-paired qt), 256 thr = 4 waves (q-rowgroup x kv-half).
// 32x32x16 frags, reg-staged K/V dbuf (XOR swizzle), 1 barrier/tile,
// in-register P-exchange (no Ps LDS), defer-max, end-merge aliasing Ks/VTs.
// QK uses TWO accumulators (even/odd k-steps) to halve the serial MFMA chain.
__global__ __launch_bounds__(256, 2) void attn_kernel(
    const u16* __restrict__ Q, const u16* __restrict__ Kc,
    const u16* __restrict__ VT, u16* __restrict__ Out)
{
  __shared__ u16 Ks[2][64 * 128];   // 32 KB; merge: f32 Obuf 64x128
  __shared__ u16 VTs[2][128 * 64];  // 32 KB; merge: Lm/Ll

  const int x = blockIdx.x;
  int qt, h;
  if (x < 256) { qt = x & 31; h = x >> 5; }
  else         { int xp = x - 256; qt = 31 - (xp & 31); h = 8 + (xp >> 5); }
  const int kvh = h >> 2;
  const int tid  = threadIdx.x;
  const int lane = tid & 63;
  const int wid  = tid >> 6;
  const int kvg  = wid & 1;      // kv-half of each tile
  const int rowg = wid >> 1;     // q-row group (32 rows)
  const int ln   = lane & 31;
  const int hi   = lane >> 5;

  const int NT = qt + 1;

  // Q B-frags: col=q=ln, k = ks*16 + hi*8 + j
  bf16x8 qf[8];
  {
    const u16* qa = Q + (size_t)(qt*64 + rowg*32 + ln) * E_DIM + h * HD + hi * 8;
    #pragma unroll
    for (int ks = 0; ks < 8; ++ks)
      qf[ks] = *reinterpret_cast<const bf16x8*>(qa + ks * 16);
  }

  f32x16 o4[4];
  #pragma unroll
  for (int d = 0; d < 4; ++d)
    #pragma unroll
    for (int r = 0; r < 16; ++r) o4[d][r] = 0.f;
  float mr = -1e30f, ls = 0.f;

  u16x8 kreg[4], vreg[4];
  const u16* kbase = Kc + kvh * HD;
  const u16* vbase = VT + (size_t)(kvh * HD) * S_LEN;

  auto stage_load = [&](int t) {
    #pragma unroll
    for (int i = 0; i < 4; ++i) {
      int c = i * 256 + tid;
      kreg[i] = *reinterpret_cast<const u16x8*>(
          kbase + (size_t)(t*64 + (c >> 4)) * KVD + (c & 15) * 8);
      vreg[i] = *reinterpret_cast<const u16x8*>(
          vbase + (size_t)(c >> 3) * S_LEN + t*64 + (c & 7) * 8);
    }
  };
  auto stage_write = [&](int b) {
    #pragma unroll
    for (int i = 0; i < 4; ++i) {
      int c = i * 256 + tid;
      int kr = c >> 4, kc = c & 15;
      *reinterpret_cast<u16x8*>(&Ks[b][kr*128 + (kc ^ (kr & 7))*8]) = kreg[i];
      int vr = c >> 3, vc = c & 7;
      *reinterpret_cast<u16x8*>(&VTs[b][vr*64 + (vc ^ (vr & 7))*8]) = vreg[i];
    }
  };

  int p = 0;
  stage_load(0);
  stage_write(0);
  __syncthreads();

  const int krow = kvg*32 + ln;   // K A-frag row (kv within tile)

  for (int t = 0; t < NT; ++t) {
    if (t + 1 < NT) stage_load(t + 1);  // latency hides under compute

    // S^T = mfma(K, Q): two accumulators halve the serial MFMA chain
    f32x16 st0, st1;
    #pragma unroll
    for (int r = 0; r < 16; ++r) { st0[r] = 0.f; st1[r] = 0.f; }
    __builtin_amdgcn_s_setprio(1);
    #pragma unroll
    for (int j = 0; j < 4; ++j) {
      bf16x8 kfrA = *reinterpret_cast<const bf16x8*>(
          &Ks[p][krow*128 + (((2*j)*2 + hi) ^ (ln & 7))*8]);
      st0 = __builtin_amdgcn_mfma_f32_32x32x16_bf16(kfrA, qf[2*j], st0, 0, 0, 0);
      bf16x8 kfrB = *reinterpret_cast<const bf16x8*>(
          &Ks[p][krow*128 + (((2*j+1)*2 + hi) ^ (ln & 7))*8]);
      st1 = __builtin_amdgcn_mfma_f32_32x32x16_bf16(kfrB, qf[2*j+1], st1, 0, 0, 0);
    }
    __builtin_amdgcn_s_setprio(0);
    f32x16 st = st0 + st1;

    if (t == qt) {  // causal mask on diagonal tile
      #pragma unroll
      for (int reg = 0; reg < 16; ++reg) {
        int kvl = kvg*32 + 4*hi + (reg & 3) + 8*(reg >> 2);
        if (kvl > rowg*32 + ln) st[reg] = -1e30f;
      }
    }

    // row max for q=ln over this wave's 32 kv: in-reg tree + 1 cross-hi shfl
    float pm = -1e30f;
    #pragma unroll
    for (int reg = 0; reg < 16; ++reg) pm = fmaxf(pm, st[reg]);
    pm = fmaxf(pm, __shfl_xor(pm, 32));

    if (!__all(pm - mr <= 8.0f)) {  // defer-max rescale (rare)
      float nm = fmaxf(mr, pm);
      float alpha = __expf(mr - nm);
      ls *= alpha;
      mr = nm;
      #pragma unroll
      for (int reg = 0; reg < 16; ++reg) {
        int crow = (reg & 3) + 8*(reg >> 2) + 4*hi;
        float ar = __shfl(alpha, crow);
        #pragma unroll
        for (int d = 0; d < 4; ++d) o4[d][reg] *= ar;
      }
    }

    float pv[16];
    float sum = 0.f;
    #pragma unroll
    for (int reg = 0; reg < 16; ++reg) {
      pv[reg] = __expf(st[reg] - mr);
      sum += pv[reg];
    }
    sum += __shfl_xor(sum, 32);
    ls += sum;

    // P -> A-frags in-register: pa[ks] = P[q=ln][kv = ks*16 + hi*8 + 0..7].
    // own groupA (regs 8ks..+3) = kv ks*16+4hi+0..3; groupB (regs 8ks+4..+7)
    // = kv ks*16+8+4hi+0..3. hi=0 sends B / keeps A; hi=1 sends A / keeps B.
    bf16x8 pa[2];
    #pragma unroll
    for (int ks = 0; ks < 2; ++ks) {
      bf16x4 A4, B4;
      #pragma unroll
      for (int j = 0; j < 4; ++j) {
        A4[j] = (__bf16)pv[ks*8 + j];
        B4[j] = (__bf16)pv[ks*8 + 4 + j];
      }
      u32x2 uA = __builtin_bit_cast(u32x2, A4);
      u32x2 uB = __builtin_bit_cast(u32x2, B4);
      unsigned sx = hi ? uA[0] : uB[0];
      unsigned sy = hi ? uA[1] : uB[1];
      unsigned rx = __shfl_xor(sx, 32);
      unsigned ry = __shfl_xor(sy, 32);
      u32x4 w;
      w[0] = hi ? rx : uA[0];
      w[1] = hi ? ry : uA[1];
      w[2] = hi ? uB[0] : rx;
      w[3] = hi ? uB[1] : ry;
      pa[ks] = __builtin_bit_cast(bf16x8, w);
    }

    // O += P * V over this wave's kv-half (4 independent d chains)
    __builtin_amdgcn_s_setprio(1);
    #pragma unroll
    for (int d = 0; d < 4; ++d) {
      int vrow = d*32 + ln;
      #pragma unroll
      for (int ks = 0; ks < 2; ++ks) {
        bf16x8 vb = *reinterpret_cast<const bf16x8*>(
            &VTs[p][vrow*64 + ((kvg*4 + ks*2 + hi) ^ (ln & 7))*8]);
        o4[d] = __builtin_amdgcn_mfma_f32_32x32x16_bf16(pa[ks], vb, o4[d], 0, 0, 0);
      }
    }
    __builtin_amdgcn_s_setprio(0);

    if (t + 1 < NT) {
      stage_write(p ^ 1);  // vmcnt wait lands here, after compute
      __syncthreads();     // single barrier per tile
      p ^= 1;
    }
  }

  // -------- merge kv-halves: kvg=1 publishes, kvg=0 combines + writes --------
  __syncthreads();                         // all reads of Ks/VTs done
  float* Obuf = (float*)&Ks[0][0];         // 64 x 128 f32 = 32 KB exact
  float* Lbuf = (float*)&VTs[0][0];        // Lm[64] | Ll[64]
  if (kvg == 1) {
    if (hi == 0) { Lbuf[rowg*32 + ln] = mr; Lbuf[64 + rowg*32 + ln] = ls; }
    #pragma unroll
    for (int reg = 0; reg < 16; ++reg) {
      int crow = (reg & 3) + 8*(reg >> 2) + 4*hi;
      #pragma unroll
      for (int d = 0; d < 4; ++d)
        Obuf[(rowg*32 + crow)*128 + d*32 + ln] = o4[d][reg];
    }
  }
  __syncthreads();
  if (kvg == 0) {
    float mB = Lbuf[rowg*32 + ln];        // partner stats for q = ln
    float lB = Lbuf[64 + rowg*32 + ln];
    float m  = fmaxf(mr, mB);
    float a0 = __expf(mr - m);
    float a1 = __expf(mB - m);
    float inv = 1.0f / (ls*a0 + lB*a1);
    #pragma unroll
    for (int reg = 0; reg < 16; ++reg) {
      int crow = (reg & 3) + 8*(reg >> 2) + 4*hi;
      float a0r = __shfl(a0, crow);
      float a1r = __shfl(a1, crow);
      float ivr = __shfl(inv, crow);
      int grow = qt*64 + rowg*32 + crow;
      #pragma unroll
      for (int d = 0; d < 4; ++d) {
        float v = (o4[d][reg]*a0r +
                   Obuf[(rowg*32 + crow)*128 + d*32 + ln]*a1r) * ivr;
        Out[(size_t)grow * E_DIM + h * HD + d*32 + ln] =
            __builtin_bit_cast(u16, (__bf16)v);
      }
    }
  }
}

// ---------------- launch ----------------
extern "C" void kernel_launch(void* const* d_in, const int* in_sizes, int n_in,
                              void* d_out, int out_size, void* d_ws, size_t ws_size,
                              hipStream_t stream)
{
  const float* x  = (const float*)d_in[0];
  const float* Wq = (const float*)d_in[1];
  const float* Wk = (const float*)d_in[2];
  const float* Wv = (const float*)d_in[3];
  const float* Wo = (const float*)d_in[4];
  const float* bo = (const float*)d_in[5];
  float* out = (float*)d_out;

  char* w = (char*)d_ws;
  u16*    xb   = (u16*)(w);                   // 8 MB  x bf16 (2048x2048)
  u16*    Wcat = (u16*)(w + (8u  << 20));     // 12 MB [Wq;Wk;Wv] bf16 (3072x2048)
  u16*    Wob  = (u16*)(w + (20u << 20));     // 8 MB  Wo bf16
  float2* tab  = (float2*)(w + (28u << 20));  // 1 MB  rope table (2048x64)
  u16*    qb   = (u16*)(w + (30u << 20));     // 8 MB  q bf16 roped+scaled
  u16*    kb   = (u16*)(w + (38u << 20));     // 2 MB  k bf16 roped
  u16*    vT   = (u16*)(w + (40u << 20));     // 2 MB  v^T bf16 (512x2048)
  u16*    attn = (u16*)(w + (42u << 20));     // 8 MB  attention out bf16
  (void)ws_size; (void)in_sizes; (void)n_in; (void)out_size;

  cast_all_kernel<<<14848, 256, 0, stream>>>(x, Wq, Wk, Wv, Wo, xb, Wcat, Wob, tab);

  gemm_bt_kernel<false, 2><<<dim3(NQKV/128, S_LEN/64), 256, 0, stream>>>(
      xb, Wcat, nullptr, nullptr, tab, qb, kb, vT, S_LEN, NQKV, E_DIM);

  attn_kernel<<<512, 256, 0, stream>>>(qb, kb, vT, attn);

  gemm_bt_kernel<true, 0><<<dim3(E_DIM/128, S_LEN/64), 256, 0, stream>>>(
      attn, Wob, out, bo, nullptr, nullptr, nullptr, nullptr, S_LEN, E_DIM, E_DIM);
}

// Round 17
// 129.818 us; speedup vs baseline: 1.0741x; 1.0052x over previous
//
#include <hip/hip_runtime.h>
#include <stdint.h>

typedef unsigned short u16;
typedef float  f32x4  __attribute__((ext_vector_type(4)));
typedef float  f32x16 __attribute__((ext_vector_type(16)));
typedef __bf16 bf16x8 __attribute__((ext_vector_type(8)));
typedef __bf16 bf16x4 __attribute__((ext_vector_type(4)));
typedef unsigned short u16x8 __attribute__((ext_vector_type(8)));
typedef unsigned short u16x4v __attribute__((ext_vector_type(4)));
typedef unsigned int u32x2 __attribute__((ext_vector_type(2)));
typedef unsigned int u32x4 __attribute__((ext_vector_type(4)));

#define S_LEN 2048
#define E_DIM 2048
#define HD    128
#define QH    16
#define KVH   4
#define KVD   512
#define NQKV  3072
#define QK_SCALE 0.08838834764831845f  // 1/sqrt(128)

#define AS1 __attribute__((address_space(1)))
#define AS3 __attribute__((address_space(3)))

__device__ __forceinline__ u16 f2bf(float f) {
  union { float f; uint32_t u; } v; v.f = f;
  return (u16)((v.u + 0x7FFFu + ((v.u >> 16) & 1u)) >> 16);
}

// ---------------- fused cast fp32->bf16 (5 tensors) + RoPE trig table ----------
__global__ void cast_all_kernel(const float* __restrict__ x, const float* __restrict__ Wq,
                                const float* __restrict__ Wk, const float* __restrict__ Wv,
                                const float* __restrict__ Wo,
                                u16* __restrict__ xb, u16* __restrict__ Wcat,
                                u16* __restrict__ Wob, float2* __restrict__ tab) {
  int i = blockIdx.x * blockDim.x + threadIdx.x;
  if (i >= 3670016) {           // rope table
    int j = i - 3670016;        // 0 .. 131071
    int s = j >> 6, pidx = j & 63;
    float inv = exp2f((float)pidx * (-13.287712379549449f / 64.0f));  // 10000^(-p/64)
    float sn, cs;
    sincosf((float)s * inv, &sn, &cs);
    tab[j] = make_float2(cs, sn);
    return;
  }
  const float* src; u16* dst;
  if (i < (1 << 20))                       { src = x  + (size_t)i * 4;  dst = xb + (size_t)i * 4; }
  else if (i < (2 << 20))                  { size_t j = i - (1 << 20);  src = Wq + j * 4; dst = Wcat + j * 4; }
  else if (i < (2 << 20) + (1 << 18))      { size_t j = i - (2 << 20);  src = Wk + j * 4; dst = Wcat + (size_t)E_DIM * E_DIM + j * 4; }
  else if (i < (2 << 20) + (2 << 18))      { size_t j = i - (2 << 20) - (1 << 18); src = Wv + j * 4; dst = Wcat + (size_t)(E_DIM + KVD) * E_DIM + j * 4; }
  else                                     { size_t j = i - (2 << 20) - (2 << 18); src = Wo + j * 4; dst = Wob + j * 4; }
  float4 f = *reinterpret_cast<const float4*>(src);
  u16x4v o;
  o[0] = f2bf(f.x); o[1] = f2bf(f.y); o[2] = f2bf(f.z); o[3] = f2bf(f.w);
  *reinterpret_cast<u16x4v*>(dst) = o;
}

// ---------------- GEMM: C[M,N] = A[M,K] * B[N,K]^T, bf16 in -------------------
// 64x128 tile (M x N), BK=64, 256 threads = 4 waves (each owns 64x32).
// T1 XCD-aware bijective block swizzle (nwg % 8 == 0 for both call sites):
// each XCD gets a contiguous chunk spanning whole M-rows -> A-panel L2-local.
// MODE 0: fp32 C + bias.  MODE 2: fused QKV epilogue (RoPE + V-transpose).
template<bool BIAS, int MODE>
__global__ __launch_bounds__(256) void gemm_bt_kernel(
    const u16* __restrict__ A, const u16* __restrict__ B,
    float* __restrict__ C, const float* __restrict__ bias,
    const float2* __restrict__ tab, u16* __restrict__ qb,
    u16* __restrict__ kb, u16* __restrict__ vTp,
    int M, int N, int K)
{
  __shared__ u16 As[2][64 * 64];    // 8 KB x2
  __shared__ u16 Bs[2][128 * 64];   // 16 KB x2

  const int tid  = threadIdx.x;
  const int lane = tid & 63;
  const int wid  = tid >> 6;        // 0..3
  const int wc   = wid * 32;
  const int lr   = lane & 15;
  const int kg   = lane >> 4;
  const int sw   = lr & 7;

  // XCD swizzle: bid -> contiguous per-XCD chunk (bijective since nwg%8==0)
  const int nbx = gridDim.x;
  const int nwg = nbx * gridDim.y;
  const int bid = blockIdx.y * nbx + blockIdx.x;
  const int cpx = nwg >> 3;
  const int swzb = (bid & 7) * cpx + (bid >> 3);
  const int bm = (swzb / nbx) * 64;
  const int bn = (swzb % nbx) * 128;

  f32x4 acc[4][2];
  #pragma unroll
  for (int r = 0; r < 4; ++r)
    #pragma unroll
    for (int c = 0; c < 2; ++c) acc[r][c] = (f32x4){0.f, 0.f, 0.f, 0.f};

  const int srow   = wid * 8 + (lane >> 3);
  const int schunk = (lane & 7) ^ (lane >> 3);

  const u16* gA = A + (size_t)(bm + srow) * K + schunk * 8;
  const u16* gB = B + (size_t)(bn + srow) * K + schunk * 8;

  auto stage = [&](int buf, int kt) {
    #pragma unroll
    for (int i = 0; i < 2; ++i)
      __builtin_amdgcn_global_load_lds(
          (const AS1 void*)(gA + (size_t)i * 32 * K + kt),
          (AS3 void*)(&As[buf][(wid*8 + i*32) * 64]), 16, 0, 0);
    #pragma unroll
    for (int i = 0; i < 4; ++i)
      __builtin_amdgcn_global_load_lds(
          (const AS1 void*)(gB + (size_t)i * 32 * K + kt),
          (AS3 void*)(&Bs[buf][(wid*8 + i*32) * 64]), 16, 0, 0);
  };

  stage(0, 0);
  __syncthreads();

  int cur = 0;
  for (int kt = 0; kt < K; kt += 64) {
    if (kt + 64 < K) stage(cur ^ 1, kt + 64);
    #pragma unroll
    for (int kk = 0; kk < 2; ++kk) {
      bf16x8 af[4], bfr[2];
      #pragma unroll
      for (int r = 0; r < 4; ++r)
        af[r] = *reinterpret_cast<const bf16x8*>(
            &As[cur][(r*16 + lr)*64 + ((kk*4 + kg) ^ sw)*8]);
      #pragma unroll
      for (int c = 0; c < 2; ++c)
        bfr[c] = *reinterpret_cast<const bf16x8*>(
            &Bs[cur][(wc + c*16 + lr)*64 + ((kk*4 + kg) ^ sw)*8]);
      #pragma unroll
      for (int r = 0; r < 4; ++r)
        #pragma unroll
        for (int c = 0; c < 2; ++c)
          acc[r][c] = __builtin_amdgcn_mfma_f32_16x16x32_bf16(af[r], bfr[c], acc[r][c], 0, 0, 0);
    }
    __syncthreads();
    cur ^= 1;
  }

  const int crow = kg * 4;
  #pragma unroll
  for (int r = 0; r < 4; ++r) {
    #pragma unroll
    for (int c = 0; c < 2; ++c) {
      int gr = bm + r*16 + crow;
      int gc = bn + wc + c*16 + lr;
      if constexpr (MODE == 0) {
        float badd = BIAS ? bias[gc] : 0.0f;
        #pragma unroll
        for (int reg = 0; reg < 4; ++reg)
          C[(size_t)(gr + reg)*N + gc] = acc[r][c][reg] + badd;
      } else {  // MODE 2: fused QKV epilogue
        if (gc < E_DIM + KVD) {
          int pidx = (gc & 127) >> 1;
          bool odd = lr & 1;
          #pragma unroll
          for (int reg = 0; reg < 4; ++reg) {
            float val = acc[r][c][reg];
            float oth = __shfl_xor(val, 1);
            float2 cs = tab[(gr + reg) * 64 + pidx];
            float o = odd ? (oth * cs.y + val * cs.x)
                          : (val * cs.x - oth * cs.y);
            if (gc < E_DIM)
              qb[(size_t)(gr + reg) * E_DIM + gc] = f2bf(o * QK_SCALE);
            else
              kb[(size_t)(gr + reg) * KVD + (gc - E_DIM)] = f2bf(o);
          }
        } else {
          bf16x4 pk;
          #pragma unroll
          for (int reg = 0; reg < 4; ++reg) pk[reg] = (__bf16)acc[r][c][reg];
          *reinterpret_cast<bf16x4*>(
              &vTp[(size_t)(gc - E_DIM - KVD) * S_LEN + gr]) = pk;
        }
      }
    }
  }
}

// ---------------- Flash attention (causal, GQA 4:1) -- r14 core (best) ---------
// 512 blocks (flip-paired qt), 256 thr = 4 waves (q-rowgroup x kv-half).
// 32x32x16 frags, reg-staged K/V dbuf (XOR swizzle), 1 barrier/tile,
// in-register P-exchange (no Ps LDS), defer-max, end-merge aliasing Ks/VTs.
__global__ __launch_bounds__(256, 2) void attn_kernel(
    const u16* __restrict__ Q, const u16* __restrict__ Kc,
    const u16* __restrict__ VT, u16* __restrict__ Out)
{
  __shared__ u16 Ks[2][64 * 128];   // 32 KB; merge: f32 Obuf 64x128
  __shared__ u16 VTs[2][128 * 64];  // 32 KB; merge: Lm/Ll

  const int x = blockIdx.x;
  int qt, h;
  if (x < 256) { qt = x & 31; h = x >> 5; }
  else         { int xp = x - 256; qt = 31 - (xp & 31); h = 8 + (xp >> 5); }
  const int kvh = h >> 2;
  const int tid  = threadIdx.x;
  const int lane = tid & 63;
  const int wid  = tid >> 6;
  const int kvg  = wid & 1;      // kv-half of each tile
  const int rowg = wid >> 1;     // q-row group (32 rows)
  const int ln   = lane & 31;
  const int hi   = lane >> 5;

  const int NT = qt + 1;

  // Q B-frags: col=q=ln, k = ks*16 + hi*8 + j
  bf16x8 qf[8];
  {
    const u16* qa = Q + (size_t)(qt*64 + rowg*32 + ln) * E_DIM + h * HD + hi * 8;
    #pragma unroll
    for (int ks = 0; ks < 8; ++ks)
      qf[ks] = *reinterpret_cast<const bf16x8*>(qa + ks * 16);
  }

  f32x16 o4[4];
  #pragma unroll
  for (int d = 0; d < 4; ++d)
    #pragma unroll
    for (int r = 0; r < 16; ++r) o4[d][r] = 0.f;
  float mr = -1e30f, ls = 0.f;

  u16x8 kreg[4], vreg[4];
  const u16* kbase = Kc + kvh * HD;
  const u16* vbase = VT + (size_t)(kvh * HD) * S_LEN;

  auto stage_load = [&](int t) {
    #pragma unroll
    for (int i = 0; i < 4; ++i) {
      int c = i * 256 + tid;
      kreg[i] = *reinterpret_cast<const u16x8*>(
          kbase + (size_t)(t*64 + (c >> 4)) * KVD + (c & 15) * 8);
      vreg[i] = *reinterpret_cast<const u16x8*>(
          vbase + (size_t)(c >> 3) * S_LEN + t*64 + (c & 7) * 8);
    }
  };
  auto stage_write = [&](int b) {
    #pragma unroll
    for (int i = 0; i < 4; ++i) {
      int c = i * 256 + tid;
      int kr = c >> 4, kc = c & 15;
      *reinterpret_cast<u16x8*>(&Ks[b][kr*128 + (kc ^ (kr & 7))*8]) = kreg[i];
      int vr = c >> 3, vc = c & 7;
      *reinterpret_cast<u16x8*>(&VTs[b][vr*64 + (vc ^ (vr & 7))*8]) = vreg[i];
    }
  };

  int p = 0;
  stage_load(0);
  stage_write(0);
  __syncthreads();

  const int krow = kvg*32 + ln;   // K A-frag row (kv within tile)

  for (int t = 0; t < NT; ++t) {
    if (t + 1 < NT) stage_load(t + 1);  // latency hides under compute

    // S^T = mfma(K, Q): lane (ln,hi) -> S[kv = kvg*32+4hi+(reg&3)+8(reg>>2)][q=ln]
    f32x16 st;
    #pragma unroll
    for (int r = 0; r < 16; ++r) st[r] = 0.f;
    __builtin_amdgcn_s_setprio(1);
    #pragma unroll
    for (int ks = 0; ks < 8; ++ks) {
      bf16x8 kfr = *reinterpret_cast<const bf16x8*>(
          &Ks[p][krow*128 + ((ks*2 + hi) ^ (ln & 7))*8]);
      st = __builtin_amdgcn_mfma_f32_32x32x16_bf16(kfr, qf[ks], st, 0, 0, 0);
    }
    __builtin_amdgcn_s_setprio(0);

    if (t == qt) {  // causal mask on diagonal tile
      #pragma unroll
      for (int reg = 0; reg < 16; ++reg) {
        int kvl = kvg*32 + 4*hi + (reg & 3) + 8*(reg >> 2);
        if (kvl > rowg*32 + ln) st[reg] = -1e30f;
      }
    }

    // row max for q=ln over this wave's 32 kv: in-reg tree + 1 cross-hi shfl
    float pm = -1e30f;
    #pragma unroll
    for (int reg = 0; reg < 16; ++reg) pm = fmaxf(pm, st[reg]);
    pm = fmaxf(pm, __shfl_xor(pm, 32));

    if (!__all(pm - mr <= 8.0f)) {  // defer-max rescale (rare)
      float nm = fmaxf(mr, pm);
      float alpha = __expf(mr - nm);
      ls *= alpha;
      mr = nm;
      #pragma unroll
      for (int reg = 0; reg < 16; ++reg) {
        int crow = (reg & 3) + 8*(reg >> 2) + 4*hi;
        float ar = __shfl(alpha, crow);
        #pragma unroll
        for (int d = 0; d < 4; ++d) o4[d][reg] *= ar;
      }
    }

    float pv[16];
    float sum = 0.f;
    #pragma unroll
    for (int reg = 0; reg < 16; ++reg) {
      pv[reg] = __expf(st[reg] - mr);
      sum += pv[reg];
    }
    sum += __shfl_xor(sum, 32);
    ls += sum;

    // P -> A-frags in-register: pa[ks] = P[q=ln][kv = ks*16 + hi*8 + 0..7].
    // own groupA (regs 8ks..+3) = kv ks*16+4hi+0..3; groupB (regs 8ks+4..+7)
    // = kv ks*16+8+4hi+0..3. hi=0 sends B / keeps A; hi=1 sends A / keeps B.
    bf16x8 pa[2];
    #pragma unroll
    for (int ks = 0; ks < 2; ++ks) {
      bf16x4 A4, B4;
      #pragma unroll
      for (int j = 0; j < 4; ++j) {
        A4[j] = (__bf16)pv[ks*8 + j];
        B4[j] = (__bf16)pv[ks*8 + 4 + j];
      }
      u32x2 uA = __builtin_bit_cast(u32x2, A4);
      u32x2 uB = __builtin_bit_cast(u32x2, B4);
      unsigned sx = hi ? uA[0] : uB[0];
      unsigned sy = hi ? uA[1] : uB[1];
      unsigned rx = __shfl_xor(sx, 32);
      unsigned ry = __shfl_xor(sy, 32);
      u32x4 w;
      w[0] = hi ? rx : uA[0];
      w[1] = hi ? ry : uA[1];
      w[2] = hi ? uB[0] : rx;
      w[3] = hi ? uB[1] : ry;
      pa[ks] = __builtin_bit_cast(bf16x8, w);
    }

    // O += P * V over this wave's kv-half (4 independent d chains)
    __builtin_amdgcn_s_setprio(1);
    #pragma unroll
    for (int d = 0; d < 4; ++d) {
      int vrow = d*32 + ln;
      #pragma unroll
      for (int ks = 0; ks < 2; ++ks) {
        bf16x8 vb = *reinterpret_cast<const bf16x8*>(
            &VTs[p][vrow*64 + ((kvg*4 + ks*2 + hi) ^ (ln & 7))*8]);
        o4[d] = __builtin_amdgcn_mfma_f32_32x32x16_bf16(pa[ks], vb, o4[d], 0, 0, 0);
      }
    }
    __builtin_amdgcn_s_setprio(0);

    if (t + 1 < NT) {
      stage_write(p ^ 1);  // vmcnt wait lands here, after compute
      __syncthreads();     // single barrier per tile
      p ^= 1;
    }
  }

  // -------- merge kv-halves: kvg=1 publishes, kvg=0 combines + writes --------
  __syncthreads();                         // all reads of Ks/VTs done
  float* Obuf = (float*)&Ks[0][0];         // 64 x 128 f32 = 32 KB exact
  float* Lbuf = (float*)&VTs[0][0];        // Lm[64] | Ll[64]
  if (kvg == 1) {
    if (hi == 0) { Lbuf[rowg*32 + ln] = mr; Lbuf[64 + rowg*32 + ln] = ls; }
    #pragma unroll
    for (int reg = 0; reg < 16; ++reg) {
      int crow = (reg & 3) + 8*(reg >> 2) + 4*hi;
      #pragma unroll
      for (int d = 0; d < 4; ++d)
        Obuf[(rowg*32 + crow)*128 + d*32 + ln] = o4[d][reg];
    }
  }
  __syncthreads();
  if (kvg == 0) {
    float mB = Lbuf[rowg*32 + ln];        // partner stats for q = ln
    float lB = Lbuf[64 + rowg*32 + ln];
    float m  = fmaxf(mr, mB);
    float a0 = __expf(mr - m);
    float a1 = __expf(mB - m);
    float inv = 1.0f / (ls*a0 + lB*a1);
    #pragma unroll
    for (int reg = 0; reg < 16; ++reg) {
      int crow = (reg & 3) + 8*(reg >> 2) + 4*hi;
      float a0r = __shfl(a0, crow);
      float a1r = __shfl(a1, crow);
      float ivr = __shfl(inv, crow);
      int grow = qt*64 + rowg*32 + crow;
      #pragma unroll
      for (int d = 0; d < 4; ++d) {
        float v = (o4[d][reg]*a0r +
                   Obuf[(rowg*32 + crow)*128 + d*32 + ln]*a1r) * ivr;
        Out[(size_t)grow * E_DIM + h * HD + d*32 + ln] =
            __builtin_bit_cast(u16, (__bf16)v);
      }
    }
  }
}

// ---------------- launch ----------------
extern "C" void kernel_launch(void* const* d_in, const int* in_sizes, int n_in,
                              void* d_out, int out_size, void* d_ws, size_t ws_size,
                              hipStream_t stream)
{
  const float* x  = (const float*)d_in[0];
  const float* Wq = (const float*)d_in[1];
  const float* Wk = (const float*)d_in[2];
  const float* Wv = (const float*)d_in[3];
  const float* Wo = (const float*)d_in[4];
  const float* bo = (const float*)d_in[5];
  float* out = (float*)d_out;

  char* w = (char*)d_ws;
  u16*    xb   = (u16*)(w);                   // 8 MB  x bf16 (2048x2048)
  u16*    Wcat = (u16*)(w + (8u  << 20));     // 12 MB [Wq;Wk;Wv] bf16 (3072x2048)
  u16*    Wob  = (u16*)(w + (20u << 20));     // 8 MB  Wo bf16
  float2* tab  = (float2*)(w + (28u << 20));  // 1 MB  rope table (2048x64)
  u16*    qb   = (u16*)(w + (30u << 20));     // 8 MB  q bf16 roped+scaled
  u16*    kb   = (u16*)(w + (38u << 20));     // 2 MB  k bf16 roped
  u16*    vT   = (u16*)(w + (40u << 20));     // 2 MB  v^T bf16 (512x2048)
  u16*    attn = (u16*)(w + (42u << 20));     // 8 MB  attention out bf16
  (void)ws_size; (void)in_sizes; (void)n_in; (void)out_size;

  cast_all_kernel<<<14848, 256, 0, stream>>>(x, Wq, Wk, Wv, Wo, xb, Wcat, Wob, tab);

  gemm_bt_kernel<false, 2><<<dim3(NQKV/128, S_LEN/64), 256, 0, stream>>>(
      xb, Wcat, nullptr, nullptr, tab, qb, kb, vT, S_LEN, NQKV, E_DIM);

  attn_kernel<<<512, 256, 0, stream>>>(qb, kb, vT, attn);

  gemm_bt_kernel<true, 0><<<dim3(E_DIM/128, S_LEN/64), 256, 0, stream>>>(
      attn, Wob, out, bo, nullptr, nullptr, nullptr, nullptr, S_LEN, E_DIM, E_DIM);
}